// Round 1
// baseline (260.888 us; speedup 1.0000x reference)
//
#include <hip/hip_runtime.h>
#include <math.h>

#define TT 512
#define BB 64
#define EE 1024
#define NN 128
#define TEMP 0.1f
#define EPSF 1e-8f

// ---------------------------------------------------------------------------
// Kernel 1: one block (1024 threads) per t. Thread e owns feature e.
// Computes per_t[t] = -cos(orig,adv)/TEMP + log(sum_e exp(cos_neg[e]/TEMP))
// ---------------------------------------------------------------------------
__global__ __launch_bounds__(1024) void contloss_main(
    const int*   __restrict__ index,
    const float* __restrict__ z1,
    const float* __restrict__ z2,
    const int*   __restrict__ neg_s,
    const int*   __restrict__ neg_w,
    float*       __restrict__ per_t)
{
    const int t = blockIdx.x;
    const int e = threadIdx.x;            // 0..1023 == feature index

    __shared__ int rowoff[NN];            // element offsets into z1 (max ~33.5M, fits int)
    __shared__ float4 red[16];            // cross-wave reduction scratch (16 waves)

    if (e < NN) {
        int s = neg_s[t * NN + e];
        int w = neg_w[t * NN + e];
        rowoff[e] = (s * BB + w) * EE;
    }
    __syncthreads();

    const int idx = index[t];             // uniform across block
    const size_t anchor = ((size_t)t * BB + (size_t)idx) * EE;
    const float orig = z1[anchor + e];
    const float adv  = z2[anchor + e];

    // ---- negative gather: per-feature sum and sum-of-squares over 128 rows
    float s1 = 0.f, s2 = 0.f;
#pragma unroll 4
    for (int j = 0; j < NN; ++j) {
        float v = z1[rowoff[j] + e];
        s1 += v;
        s2 += v * v;
    }

    // ---- cos_neg[e] and its exp term
    const float dotv  = orig * s1;
    const float nnorm = sqrtf(s2);
    const float onorm = sqrtf((float)NN) * fabsf(orig);
    const float cosn  = dotv / (fmaxf(nnorm, EPSF) * fmaxf(onorm, EPSF));
    float v0 = expf(cosn * (1.0f / TEMP));   // den contribution
    float v1 = orig * adv;                    // pos dot
    float v2 = orig * orig;                   // ||orig||^2
    float v3 = adv * adv;                     // ||adv||^2

    // ---- wave-level reduction (64 lanes)
    for (int off = 32; off > 0; off >>= 1) {
        v0 += __shfl_xor(v0, off, 64);
        v1 += __shfl_xor(v1, off, 64);
        v2 += __shfl_xor(v2, off, 64);
        v3 += __shfl_xor(v3, off, 64);
    }
    const int lane = e & 63;
    const int wid  = e >> 6;                  // 0..15
    if (lane == 0) red[wid] = make_float4(v0, v1, v2, v3);
    __syncthreads();

    // ---- cross-wave: first 16 lanes of wave 0
    if (e < 16) {
        float4 r = red[e];
        float a0 = r.x, a1 = r.y, a2 = r.z, a3 = r.w;
        for (int off = 8; off > 0; off >>= 1) {
            a0 += __shfl_xor(a0, off, 64);
            a1 += __shfl_xor(a1, off, 64);
            a2 += __shfl_xor(a2, off, 64);
            a3 += __shfl_xor(a3, off, 64);
        }
        if (e == 0) {
            const float den  = a0;
            const float na   = fmaxf(sqrtf(a2), EPSF);
            const float nb   = fmaxf(sqrtf(a3), EPSF);
            const float cosp = a1 / (na * nb);
            per_t[t] = -cosp * (1.0f / TEMP) + logf(den);
        }
    }
}

// ---------------------------------------------------------------------------
// Kernel 2: reduce the 512 per-t losses to the scalar output.
// ---------------------------------------------------------------------------
__global__ __launch_bounds__(512) void contloss_reduce(
    const float* __restrict__ per_t, float* __restrict__ out)
{
    const int tid = threadIdx.x;          // 0..511
    float v = per_t[tid];
    for (int off = 32; off > 0; off >>= 1) v += __shfl_xor(v, off, 64);

    __shared__ float red[8];
    const int lane = tid & 63, wid = tid >> 6;  // 8 waves
    if (lane == 0) red[wid] = v;
    __syncthreads();
    if (tid < 8) {
        float a = red[tid];
        for (int off = 4; off > 0; off >>= 1) a += __shfl_xor(a, off, 64);
        if (tid == 0) out[0] = a;
    }
}

extern "C" void kernel_launch(void* const* d_in, const int* in_sizes, int n_in,
                              void* d_out, int out_size, void* d_ws, size_t ws_size,
                              hipStream_t stream) {
    const int*   index = (const int*)  d_in[0];
    const float* z1    = (const float*)d_in[1];
    const float* z2    = (const float*)d_in[2];
    const int*   neg_s = (const int*)  d_in[3];
    const int*   neg_w = (const int*)  d_in[4];
    float* out   = (float*)d_out;
    float* per_t = (float*)d_ws;          // TT floats of scratch

    contloss_main<<<TT, 1024, 0, stream>>>(index, z1, z2, neg_s, neg_w, per_t);
    contloss_reduce<<<1, 512, 0, stream>>>(per_t, out);
}

// Round 2
// 259.032 us; speedup vs baseline: 1.0072x; 1.0072x over previous
//
#include <hip/hip_runtime.h>
#include <math.h>

#define TT 512
#define BB 64
#define EE 1024
#define NN 128
#define TEMP 0.1f
#define EPSF 1e-8f

// ---------------------------------------------------------------------------
// Kernel 1: one block (1024 threads) per t.
//   tid = grp*256 + sub :  grp (0..3) = row group, sub (0..255) = feature quad.
//   Each thread float4-accumulates 32 of the 128 negative rows for its
//   4 features; LDS combine across groups; vectorized epilogue + reduction.
// ---------------------------------------------------------------------------
__global__ __launch_bounds__(1024) void contloss_main(
    const int*   __restrict__ index,
    const float* __restrict__ z1,
    const float* __restrict__ z2,
    const int*   __restrict__ neg_s,
    const int*   __restrict__ neg_w,
    float*       __restrict__ per_t)
{
    const int t   = blockIdx.x;
    const int tid = threadIdx.x;
    const int sub = tid & 255;     // feature-quad index (features 4*sub..4*sub+3)
    const int grp = tid >> 8;      // row group 0..3

    __shared__ int    rowoff[NN];
    __shared__ float4 part1[4][256];   // per-group partial sums
    __shared__ float4 part2[4][256];   // per-group partial sums of squares
    __shared__ float4 red[16];         // cross-wave reduction scratch

    if (tid < NN) {
        const int s = neg_s[t * NN + tid];
        const int w = neg_w[t * NN + tid];
        rowoff[tid] = (s * BB + w) * EE;   // max ~33.5M, fits int32
    }
    __syncthreads();

    // ---- gather: 32 rows per thread, float4 per row ----
    float4 s1 = make_float4(0.f, 0.f, 0.f, 0.f);
    float4 s2 = make_float4(0.f, 0.f, 0.f, 0.f);
#pragma unroll 8
    for (int j = grp; j < NN; j += 4) {
        const float4 v = *reinterpret_cast<const float4*>(z1 + rowoff[j] + 4 * sub);
        s1.x += v.x; s1.y += v.y; s1.z += v.z; s1.w += v.w;
        s2.x += v.x * v.x; s2.y += v.y * v.y; s2.z += v.z * v.z; s2.w += v.w * v.w;
    }
    part1[grp][sub] = s1;
    part2[grp][sub] = s2;
    __syncthreads();

    // ---- epilogue: first 256 threads own their feature quad ----
    float v0 = 0.f, v1 = 0.f, v2 = 0.f, v3 = 0.f;
    if (tid < 256) {
        float4 a1 = part1[0][tid];
        float4 a2 = part2[0][tid];
#pragma unroll
        for (int g = 1; g < 4; ++g) {
            const float4 p1 = part1[g][tid];
            const float4 p2 = part2[g][tid];
            a1.x += p1.x; a1.y += p1.y; a1.z += p1.z; a1.w += p1.w;
            a2.x += p2.x; a2.y += p2.y; a2.z += p2.z; a2.w += p2.w;
        }
        const int idx = index[t];
        const size_t anchor = ((size_t)t * BB + (size_t)idx) * EE;
        const float4 og = *reinterpret_cast<const float4*>(z1 + anchor + 4 * tid);
        const float4 ad = *reinterpret_cast<const float4*>(z2 + anchor + 4 * tid);

        const float sqn = sqrtf((float)NN);
        const float og_[4] = {og.x, og.y, og.z, og.w};
        const float ad_[4] = {ad.x, ad.y, ad.z, ad.w};
        const float a1_[4] = {a1.x, a1.y, a1.z, a1.w};
        const float a2_[4] = {a2.x, a2.y, a2.z, a2.w};
#pragma unroll
        for (int c = 0; c < 4; ++c) {
            const float nnorm = sqrtf(a2_[c]);
            const float onorm = sqn * fabsf(og_[c]);
            const float cosn  = (og_[c] * a1_[c]) /
                                (fmaxf(nnorm, EPSF) * fmaxf(onorm, EPSF));
            v0 += expf(cosn * (1.0f / TEMP));
            v1 += og_[c] * ad_[c];
            v2 += og_[c] * og_[c];
            v3 += ad_[c] * ad_[c];
        }
    }

    // ---- block reduction (all 1024 threads participate; >=256 carry zeros) ----
    for (int off = 32; off > 0; off >>= 1) {
        v0 += __shfl_xor(v0, off, 64);
        v1 += __shfl_xor(v1, off, 64);
        v2 += __shfl_xor(v2, off, 64);
        v3 += __shfl_xor(v3, off, 64);
    }
    const int lane = tid & 63;
    const int wid  = tid >> 6;     // 0..15
    if (lane == 0) red[wid] = make_float4(v0, v1, v2, v3);
    __syncthreads();

    if (tid < 16) {
        float4 r = red[tid];
        float a0 = r.x, a1 = r.y, a2 = r.z, a3 = r.w;
        for (int off = 8; off > 0; off >>= 1) {
            a0 += __shfl_xor(a0, off, 64);
            a1 += __shfl_xor(a1, off, 64);
            a2 += __shfl_xor(a2, off, 64);
            a3 += __shfl_xor(a3, off, 64);
        }
        if (tid == 0) {
            const float den  = a0;
            const float na   = fmaxf(sqrtf(a2), EPSF);
            const float nb   = fmaxf(sqrtf(a3), EPSF);
            const float cosp = a1 / (na * nb);
            per_t[t] = -cosp * (1.0f / TEMP) + logf(den);
        }
    }
}

// ---------------------------------------------------------------------------
// Kernel 2: reduce the 512 per-t losses to the scalar output.
// ---------------------------------------------------------------------------
__global__ __launch_bounds__(512) void contloss_reduce(
    const float* __restrict__ per_t, float* __restrict__ out)
{
    const int tid = threadIdx.x;          // 0..511
    float v = per_t[tid];
    for (int off = 32; off > 0; off >>= 1) v += __shfl_xor(v, off, 64);

    __shared__ float red[8];
    const int lane = tid & 63, wid = tid >> 6;  // 8 waves
    if (lane == 0) red[wid] = v;
    __syncthreads();
    if (tid < 8) {
        float a = red[tid];
        for (int off = 4; off > 0; off >>= 1) a += __shfl_xor(a, off, 64);
        if (tid == 0) out[0] = a;
    }
}

extern "C" void kernel_launch(void* const* d_in, const int* in_sizes, int n_in,
                              void* d_out, int out_size, void* d_ws, size_t ws_size,
                              hipStream_t stream) {
    const int*   index = (const int*)  d_in[0];
    const float* z1    = (const float*)d_in[1];
    const float* z2    = (const float*)d_in[2];
    const int*   neg_s = (const int*)  d_in[3];
    const int*   neg_w = (const int*)  d_in[4];
    float* out   = (float*)d_out;
    float* per_t = (float*)d_ws;          // TT floats of scratch

    contloss_main<<<TT, 1024, 0, stream>>>(index, z1, z2, neg_s, neg_w, per_t);
    contloss_reduce<<<1, 512, 0, stream>>>(per_t, out);
}